// Round 1
// baseline (1902.253 us; speedup 1.0000x reference)
//
#include <hip/hip_runtime.h>
#include <math.h>

#define NBAGS 2048
#define CROWS 64
#define IND   512
#define HD1   256
#define HD2   256
#define HD3   128
#define DET1  128
#define DET2  64
#define TAUV  0.95f
#define KDROP 44   // int(64*0.7)

#define TSTRIDE 68                       // padded transposed-activation row stride (16B aligned)
#define ACT_F   (256 * TSTRIDE)          // 17408 floats
#define STG_F   (32 * TSTRIDE + 32*256)  // 2176 + 8192 = 10368 floats

// Generic fused GEMM phase: C[64][NC] = act(A[64][K] @ B[K][NC] + bias)
// A is transposed in LDS: aT[k*TSTRIDE + r]. Output written transposed: cT[c*TSTRIDE + r].
// B staged from global in 32-row K-tiles into sB.
template <int K, int NC, bool SIG>
__device__ __forceinline__ void gemm_phase(const float* __restrict__ gB,
                                           const float* __restrict__ gBias,
                                           const float* aT, float* cT, float* sB,
                                           int tid)
{
  constexpr int NQ   = (NC == 256) ? 2 : 1;
  constexpr int RPT  = (NC == 64) ? 4 : 8;
  constexpr int NCOL = NQ * 4;
  const int r0 = (NC == 64) ? ((tid >> 4) * 4) : ((tid >> 5) * 8);
  const int c0 = (NC == 64) ? ((tid & 15) * 4) : ((tid & 31) * 4);

  float acc[RPT][NCOL];
#pragma unroll
  for (int i = 0; i < RPT; ++i)
#pragma unroll
    for (int j = 0; j < NCOL; ++j) acc[i][j] = 0.0f;

  for (int kt = 0; kt < K; kt += 32) {
    __syncthreads();  // previous compute done before overwriting sB
#pragma unroll
    for (int idx = tid; idx < 8 * NC; idx += 256) {
      int row = idx / (NC / 4);
      int c4  = (idx % (NC / 4)) * 4;
      *(float4*)(sB + row * NC + c4) = *(const float4*)(gB + (kt + row) * NC + c4);
    }
    __syncthreads();
#pragma unroll 4
    for (int j = 0; j < 32; ++j) {
      const float* ap = aT + (kt + j) * TSTRIDE + r0;
      float a[RPT];
      {
        float4 a0 = *(const float4*)ap;
        a[0] = a0.x; a[1] = a0.y; a[2] = a0.z; a[3] = a0.w;
        if constexpr (RPT == 8) {
          float4 a1 = *(const float4*)(ap + 4);
          a[4] = a1.x; a[5] = a1.y; a[6] = a1.z; a[7] = a1.w;
        }
      }
      const float* bp = sB + j * NC + c0;
      float b[NCOL];
      {
        float4 b0 = *(const float4*)bp;
        b[0] = b0.x; b[1] = b0.y; b[2] = b0.z; b[3] = b0.w;
        if constexpr (NQ == 2) {
          float4 b1 = *(const float4*)(bp + 128);
          b[4] = b1.x; b[5] = b1.y; b[6] = b1.z; b[7] = b1.w;
        }
      }
#pragma unroll
      for (int i = 0; i < RPT; ++i)
#pragma unroll
        for (int jj = 0; jj < NCOL; ++jj)
          acc[i][jj] = fmaf(a[i], b[jj], acc[i][jj]);
    }
  }
  __syncthreads();  // all A reads done; safe to write cT (may alias aT / sB)
#pragma unroll
  for (int q = 0; q < NQ; ++q)
#pragma unroll
    for (int jj = 0; jj < 4; ++jj) {
      int c = c0 + q * 128 + jj;
      float bias = gBias[c];
#pragma unroll
      for (int i = 0; i < RPT; ++i) {
        float v = acc[i][q * 4 + jj] + bias;
        v = SIG ? (1.0f / (1.0f + expf(-v))) : fmaxf(v, 0.0f);
        cT[c * TSTRIDE + r0 + i] = v;
      }
    }
  __syncthreads();
}

__global__ __launch_bounds__(256, 1) void bagnet_kernel(
    const float* __restrict__ gx, const float* __restrict__ gm,
    const float* __restrict__ gu,
    const float* __restrict__ gW1, const float* __restrict__ gb1,
    const float* __restrict__ gW2, const float* __restrict__ gb2,
    const float* __restrict__ gW3, const float* __restrict__ gb3,
    const float* __restrict__ gD1, const float* __restrict__ gdb1,
    const float* __restrict__ gD2, const float* __restrict__ gdb2,
    const float* __restrict__ gD3, const float* __restrict__ gdb3,
    const float* __restrict__ gE, const float* __restrict__ geb,
    float* __restrict__ outw, float* __restrict__ outv)
{
  extern __shared__ float smf[];
  float* act = smf;            // ACT_F floats
  float* stg = smf + ACT_F;    // STG_F floats (sA_T | sB), later h_T
  __shared__ float sZ[64], sEx[64], sW2s[64], sKeep[64], sE2[64], sWf[64], sRed[128];

  const int tid = threadIdx.x;
  const int bag = blockIdx.x;

  // ---------------- Phase 1: h1 = relu(x @ W1 + b1), 64x512 @ 512x256 ----------------
  {
    const float* xg = gx + (size_t)bag * CROWS * IND;
    const int ty = tid >> 5, tx = tid & 31;
    const int r0 = ty * 8, c0 = tx * 4;
    float* sAT = stg;                    // 32 x TSTRIDE (transposed x tile)
    float* sB  = stg + 32 * TSTRIDE;     // 32 x 256

    float acc[8][8];
#pragma unroll
    for (int i = 0; i < 8; ++i)
#pragma unroll
      for (int j = 0; j < 8; ++j) acc[i][j] = 0.0f;

    for (int kt = 0; kt < IND; kt += 32) {
      __syncthreads();
      // stage x tile (64 rows x 32 k) transposed into sAT[j][r]
#pragma unroll
      for (int f = tid; f < 512; f += 256) {
        int r  = f >> 3;
        int j4 = (f & 7) * 4;
        float4 v = *(const float4*)(xg + r * IND + kt + j4);
        sAT[(j4 + 0) * TSTRIDE + r] = v.x;
        sAT[(j4 + 1) * TSTRIDE + r] = v.y;
        sAT[(j4 + 2) * TSTRIDE + r] = v.z;
        sAT[(j4 + 3) * TSTRIDE + r] = v.w;
      }
      // stage W1 tile 32 x 256
#pragma unroll
      for (int idx = tid; idx < 2048; idx += 256) {
        int row = idx >> 6;
        int c4  = (idx & 63) * 4;
        *(float4*)(sB + row * 256 + c4) = *(const float4*)(gW1 + (kt + row) * 256 + c4);
      }
      __syncthreads();
#pragma unroll 4
      for (int j = 0; j < 32; ++j) {
        const float* ap = sAT + j * TSTRIDE + r0;
        float4 a0 = *(const float4*)ap;
        float4 a1 = *(const float4*)(ap + 4);
        float a[8] = {a0.x, a0.y, a0.z, a0.w, a1.x, a1.y, a1.z, a1.w};
        const float* bp = sB + j * 256 + c0;
        float4 b0 = *(const float4*)bp;
        float4 b1 = *(const float4*)(bp + 128);
        float b[8] = {b0.x, b0.y, b0.z, b0.w, b1.x, b1.y, b1.z, b1.w};
#pragma unroll
        for (int i = 0; i < 8; ++i)
#pragma unroll
          for (int jj = 0; jj < 8; ++jj)
            acc[i][jj] = fmaf(a[i], b[jj], acc[i][jj]);
      }
    }
    __syncthreads();
    // epilogue: h1_T into act
#pragma unroll
    for (int q = 0; q < 2; ++q)
#pragma unroll
      for (int jj = 0; jj < 4; ++jj) {
        int c = c0 + q * 128 + jj;
        float bias = gb1[c];
#pragma unroll
        for (int i = 0; i < 8; ++i) {
          float v = fmaxf(acc[i][q * 4 + jj] + bias, 0.0f);
          act[c * TSTRIDE + r0 + i] = v;
        }
      }
    __syncthreads();
  }

  // ---------------- Phase 2: h2 = relu(h1 @ W2 + b2)  (act -> act) ----------------
  gemm_phase<HD1, HD2, false>(gW2, gb2, act, act, stg, tid);
  // ---------------- Phase 3: h = relu(h2 @ W3 + b3)   (act -> stg as h_T) ----------
  gemm_phase<HD2, HD3, false>(gW3, gb3, act, stg, stg, tid);
  // ---------------- Phase 4: d1 = sigmoid(h @ D1 + db1) (stg -> act+4096) ----------
  gemm_phase<HD3, DET1, true>(gD1, gdb1, stg, act + 4096, act, tid);
  // ---------------- Phase 5: d2 = sigmoid(d1 @ D2 + db2) (act+4096 -> act+12800) ---
  gemm_phase<DET1, DET2, true>(gD2, gdb2, act + 4096, act + 12800, act, tid);

  // ---------------- Phase 6: logits, gumbel softmax ----------------
  const float* d2T = act + 12800;  // [64 cols][TSTRIDE]
  if (tid < CROWS) {
    float a = gdb3[0];
    for (int k = 0; k < DET2; ++k) a = fmaf(d2T[k * TSTRIDE + tid], gD3[k], a);
    float logit = gm[(size_t)bag * CROWS + tid] * a;
    float uu = gu[(size_t)bag * CROWS + tid];
    float g = -logf(-logf(uu));
    sZ[tid] = (logit + g) * (1.0f / TAUV);
  }
  __syncthreads();
  if (tid < CROWS) {
    float mx = -1e30f;
    for (int j = 0; j < CROWS; ++j) mx = fmaxf(mx, sZ[j]);
    sEx[tid] = expf(sZ[tid] - mx);
  }
  __syncthreads();
  float w2 = 0.0f;
  if (tid < CROWS) {
    float s = 0.0f;
    for (int j = 0; j < CROWS; ++j) s += sEx[j];
    w2 = sEx[tid] / s;
    sW2s[tid] = w2;
  }
  __syncthreads();
  // ---------------- stable top-20 keep (rank >= 44 in ascending stable order) ------
  int keep = 0;
  if (tid < CROWS) {
    int cnt = 0;
    for (int j = 0; j < CROWS; ++j) {
      float vj = sW2s[j];
      cnt += (vj < w2) || (vj == w2 && j < tid);
    }
    keep = (cnt >= KDROP) ? 1 : 0;
    sKeep[tid] = (float)keep;
  }
  __syncthreads();
  float e2 = 0.0f;
  if (tid < CROWS) {
    float mk = -1e30f;
    for (int j = 0; j < CROWS; ++j)
      if (sKeep[j] > 0.5f) mk = fmaxf(mk, sW2s[j]);
    e2 = keep ? expf(w2 - mk) : 0.0f;
    sE2[tid] = e2;
  }
  __syncthreads();
  if (tid < CROWS) {
    float s2 = 0.0f;
    for (int j = 0; j < CROWS; ++j) s2 += sE2[j];
    float wf = keep ? (e2 / s2) : 0.0f;
    sWf[tid] = wf;
    outw[(size_t)bag * CROWS + tid] = wf;
  }
  __syncthreads();
  // ---------------- agg = w @ h ; out = agg @ E + eb ----------------
  if (tid < HD3) {
    const float* hT = stg;  // h_T[c][r]
    float a = 0.0f;
    for (int r = 0; r < CROWS; ++r) a = fmaf(sWf[r], hT[tid * TSTRIDE + r], a);
    sRed[tid] = a * gE[tid];
  }
  __syncthreads();
  if (tid == 0) {
    float s = geb[0];
    for (int j = 0; j < HD3; ++j) s += sRed[j];
    outv[bag] = s;
  }
}

extern "C" void kernel_launch(void* const* d_in, const int* in_sizes, int n_in,
                              void* d_out, int out_size, void* d_ws, size_t ws_size,
                              hipStream_t stream) {
  (void)in_sizes; (void)n_in; (void)d_ws; (void)ws_size; (void)out_size;
  const float* x   = (const float*)d_in[0];
  const float* m   = (const float*)d_in[1];
  const float* u   = (const float*)d_in[2];
  const float* W1  = (const float*)d_in[3];
  const float* b1  = (const float*)d_in[4];
  const float* W2  = (const float*)d_in[5];
  const float* b2  = (const float*)d_in[6];
  const float* W3  = (const float*)d_in[7];
  const float* b3  = (const float*)d_in[8];
  const float* D1  = (const float*)d_in[9];
  const float* db1 = (const float*)d_in[10];
  const float* D2  = (const float*)d_in[11];
  const float* db2 = (const float*)d_in[12];
  const float* D3  = (const float*)d_in[13];
  const float* db3 = (const float*)d_in[14];
  const float* E   = (const float*)d_in[15];
  const float* eb  = (const float*)d_in[16];
  float* outw = (float*)d_out;
  float* outv = outw + (size_t)NBAGS * CROWS;

  const size_t smem = (size_t)(ACT_F + STG_F) * sizeof(float);  // ~111 KB
  // Allow >64KB dynamic LDS (gfx950 has 160 KB/CU). Idempotent, capture-safe.
  (void)hipFuncSetAttribute((const void*)bagnet_kernel,
                            hipFuncAttributeMaxDynamicSharedMemorySize, (int)smem);

  bagnet_kernel<<<NBAGS, 256, smem, stream>>>(
      x, m, u, W1, b1, W2, b2, W3, b3, D1, db1, D2, db2, D3, db3, E, eb,
      outw, outv);
}

// Round 2
// 791.749 us; speedup vs baseline: 2.4026x; 2.4026x over previous
//
#include <hip/hip_runtime.h>
#include <math.h>

#define NBAGS 2048
#define CROWS 64
#define IND   512
#define TAUV  0.95f
#define KDROP 44   // int(64*0.7)

typedef _Float16 h8  __attribute__((ext_vector_type(8)));
typedef _Float16 h4  __attribute__((ext_vector_type(4)));
typedef float    f16v __attribute__((ext_vector_type(16)));

// ---------------------------------------------------------------------------
// Fragment-order layout for an MFMA operand plane (A: [m][k], B: [n][k]).
// Element (q32 = idx&31, tile = idx>>5, k):
//   addr = (tile*nkt + (k>>4))*528 + (idx&31)*8 + ((k>>3)&1)*264 + (k&7)
// 528 = 2*264; the 264 (instead of 256) staggers the kg-halves by 16B so the
// epilogue's per-lane b16 scatter writes land on 32 distinct banks (2-way max,
// free per m136). Lane read: one b128 at 16B-aligned address, conflict-free.
// ---------------------------------------------------------------------------
__device__ __forceinline__ int frag_roff(int lane, int tile, int t, int nkt) {
  return (tile * nkt + t) * 528 + (lane & 31) * 8 + (lane >> 5) * 264;
}

// ws element offsets (in _Float16 units). plane = (N/32)*nkt*528.
#define W1HI 0
#define W1LO 135168
#define W2HI 270336
#define W2LO 337920
#define W3HI 405504
#define W3LO 439296
#define D1HI 473088
#define D1LO 489984
#define D2HI 506880
#define D2LO 515328
#define WS_ELS 523776  // ~1.05 MB

// ---------------------------------------------------------------------------
// Prep: convert fp32 weights -> hi/lo fp16 fragment-order planes in d_ws.
// Runs every launch (d_ws is re-poisoned by the harness).
// ---------------------------------------------------------------------------
__global__ __launch_bounds__(256) void prep_weights(
    const float* __restrict__ W1, const float* __restrict__ W2,
    const float* __restrict__ W3, const float* __restrict__ D1,
    const float* __restrict__ D2, _Float16* __restrict__ ws)
{
  int e = blockIdx.x * 256 + threadIdx.x;
  const float* src; int local, nlog, nkt, offH, offL;
  if (e < 131072)      { src = W1; local = e;          nlog = 8; nkt = 32; offH = W1HI; offL = W1LO; }
  else if (e < 196608) { src = W2; local = e - 131072; nlog = 8; nkt = 16; offH = W2HI; offL = W2LO; }
  else if (e < 229376) { src = W3; local = e - 196608; nlog = 7; nkt = 16; offH = W3HI; offL = W3LO; }
  else if (e < 245760) { src = D1; local = e - 229376; nlog = 7; nkt = 8;  offH = D1HI; offL = D1LO; }
  else if (e < 253952) { src = D2; local = e - 245760; nlog = 6; nkt = 8;  offH = D2HI; offL = D2LO; }
  else return;
  int k = local >> nlog;
  int n = local & ((1 << nlog) - 1);
  float w = src[local];
  _Float16 hi = (_Float16)w;
  _Float16 lo = (_Float16)(w - (float)hi);
  int addr = ((n >> 5) * nkt + (k >> 4)) * 528 + (n & 31) * 8 + ((k >> 3) & 1) * 264 + (k & 7);
  ws[offH + addr] = hi;
  ws[offL + addr] = lo;
}

// ---------------------------------------------------------------------------
// Generic phase: C[64][N] = act(A[64][K] @ W[K][N] + bias)
// A hi/lo fp16 planes in LDS (frag order); W hi/lo from global (L2-hot ws);
// 3-product split MFMA; epilogue writes next phase's A planes (frag order).
// ---------------------------------------------------------------------------
template<int NKT, int NTILES, int ACT>   // NKT=K/16, NTILES=N/32, ACT 0=relu 1=sigmoid
__device__ __forceinline__ void gemm_phase(
    const _Float16* __restrict__ bHi, const _Float16* __restrict__ bLo,
    const float* __restrict__ bias,
    const _Float16* aHi, const _Float16* aLo,
    _Float16* oHi, _Float16* oLo,
    int wave, int lane)
{
  constexpr int NTPW = (NTILES >= 8) ? 2 : 1;
  constexpr int ONKT = NTILES * 2;   // output feeds next phase with K' = N
  const int nt0 = wave * NTPW;
  const bool active = (nt0 < NTILES);
  f16v acc[2][NTPW] = {};
  if (active) {
#pragma unroll 4
    for (int t = 0; t < NKT; ++t) {
      h8 ah0 = *(const h8*)(aHi + frag_roff(lane, 0, t, NKT));
      h8 ah1 = *(const h8*)(aHi + frag_roff(lane, 1, t, NKT));
      h8 al0 = *(const h8*)(aLo + frag_roff(lane, 0, t, NKT));
      h8 al1 = *(const h8*)(aLo + frag_roff(lane, 1, t, NKT));
#pragma unroll
      for (int nt = 0; nt < NTPW; ++nt) {
        int boff = frag_roff(lane, nt0 + nt, t, NKT);
        h8 bh = *(const h8*)(bHi + boff);
        h8 bl = *(const h8*)(bLo + boff);
        acc[0][nt] = __builtin_amdgcn_mfma_f32_32x32x16_f16(ah0, bh, acc[0][nt], 0, 0, 0);
        acc[1][nt] = __builtin_amdgcn_mfma_f32_32x32x16_f16(ah1, bh, acc[1][nt], 0, 0, 0);
        acc[0][nt] = __builtin_amdgcn_mfma_f32_32x32x16_f16(ah0, bl, acc[0][nt], 0, 0, 0);
        acc[1][nt] = __builtin_amdgcn_mfma_f32_32x32x16_f16(ah1, bl, acc[1][nt], 0, 0, 0);
        acc[0][nt] = __builtin_amdgcn_mfma_f32_32x32x16_f16(al0, bh, acc[0][nt], 0, 0, 0);
        acc[1][nt] = __builtin_amdgcn_mfma_f32_32x32x16_f16(al1, bh, acc[1][nt], 0, 0, 0);
      }
    }
    // epilogue: C/D layout col=lane&31, row=(r&3)+8*(r>>2)+4*(lane>>5)
#pragma unroll
    for (int mt = 0; mt < 2; ++mt)
#pragma unroll
      for (int nt = 0; nt < NTPW; ++nt) {
        int n = (nt0 + nt) * 32 + (lane & 31);
        float bs = bias[n];
        int t2 = n >> 4, kg = (n >> 3) & 1, j = n & 7;
#pragma unroll
        for (int r = 0; r < 16; ++r) {
          int row = (r & 3) + 8 * (r >> 2) + 4 * (lane >> 5);
          int m = mt * 32 + row;
          float v = acc[mt][nt][r] + bs;
          v = (ACT == 0) ? fmaxf(v, 0.0f) : (1.0f / (1.0f + expf(-v)));
          _Float16 hi = (_Float16)v;
          _Float16 lo = (_Float16)(v - (float)hi);
          int addr = ((m >> 5) * ONKT + t2) * 528 + (m & 31) * 8 + kg * 264 + j;
          oHi[addr] = hi;
          oLo[addr] = lo;
        }
      }
  }
  __syncthreads();
}

// ---------------------------------------------------------------------------
// Phase 1: x (fp32, global) @ W1 -> h1. Stages x in 64-k chunks into LDS,
// converting fp32 -> hi/lo fp16 frag order, double-buffered.
// ---------------------------------------------------------------------------
__device__ __forceinline__ void phase1(
    const float* __restrict__ xg,
    const _Float16* __restrict__ bHi, const _Float16* __restrict__ bLo,
    const float* __restrict__ bias,
    _Float16* xs,                 // staging: 2 bufs x (hi 4224 + lo 4224) els
    _Float16* oHi, _Float16* oLo, // h1 planes (ONKT=16)
    int tid, int wave, int lane)
{
  const int nt0 = wave * 2;
  f16v acc[2][2] = {};

  auto stage = [&](int c) {
    _Float16* sHi = xs + (c & 1) * 8448;
    _Float16* sLo = sHi + 4224;
#pragma unroll
    for (int it = 0; it < 4; ++it) {
      int flat = it * 256 + tid;
      int row = flat >> 4, c4 = flat & 15;
      float4 v = *(const float4*)(xg + row * 512 + c * 64 + c4 * 4);
      int t = c4 >> 2, kg = (c4 >> 1) & 1, j0 = (c4 & 1) * 4;
      int addr = ((row >> 5) * 4 + t) * 528 + (row & 31) * 8 + kg * 264 + j0;
      h4 hi, lo;
      hi[0] = (_Float16)v.x; lo[0] = (_Float16)(v.x - (float)hi[0]);
      hi[1] = (_Float16)v.y; lo[1] = (_Float16)(v.y - (float)hi[1]);
      hi[2] = (_Float16)v.z; lo[2] = (_Float16)(v.z - (float)hi[2]);
      hi[3] = (_Float16)v.w; lo[3] = (_Float16)(v.w - (float)hi[3]);
      *(h4*)(sHi + addr) = hi;
      *(h4*)(sLo + addr) = lo;
    }
  };

  stage(0);
  __syncthreads();
  for (int c = 0; c < 8; ++c) {
    if (c < 7) stage(c + 1);  // writes other buffer; prior reads fenced by last barrier
    const _Float16* sHi = xs + (c & 1) * 8448;
    const _Float16* sLo = sHi + 4224;
#pragma unroll
    for (int t = 0; t < 4; ++t) {
      int tg = c * 4 + t;
      h8 ah0 = *(const h8*)(sHi + frag_roff(lane, 0, t, 4));
      h8 ah1 = *(const h8*)(sHi + frag_roff(lane, 1, t, 4));
      h8 al0 = *(const h8*)(sLo + frag_roff(lane, 0, t, 4));
      h8 al1 = *(const h8*)(sLo + frag_roff(lane, 1, t, 4));
#pragma unroll
      for (int nt = 0; nt < 2; ++nt) {
        int boff = frag_roff(lane, nt0 + nt, tg, 32);
        h8 bh = *(const h8*)(bHi + boff);
        h8 bl = *(const h8*)(bLo + boff);
        acc[0][nt] = __builtin_amdgcn_mfma_f32_32x32x16_f16(ah0, bh, acc[0][nt], 0, 0, 0);
        acc[1][nt] = __builtin_amdgcn_mfma_f32_32x32x16_f16(ah1, bh, acc[1][nt], 0, 0, 0);
        acc[0][nt] = __builtin_amdgcn_mfma_f32_32x32x16_f16(ah0, bl, acc[0][nt], 0, 0, 0);
        acc[1][nt] = __builtin_amdgcn_mfma_f32_32x32x16_f16(ah1, bl, acc[1][nt], 0, 0, 0);
        acc[0][nt] = __builtin_amdgcn_mfma_f32_32x32x16_f16(al0, bh, acc[0][nt], 0, 0, 0);
        acc[1][nt] = __builtin_amdgcn_mfma_f32_32x32x16_f16(al1, bh, acc[1][nt], 0, 0, 0);
      }
    }
    __syncthreads();
  }
  // epilogue -> h1 planes (ONKT = 16)
#pragma unroll
  for (int mt = 0; mt < 2; ++mt)
#pragma unroll
    for (int nt = 0; nt < 2; ++nt) {
      int n = (nt0 + nt) * 32 + (lane & 31);
      float bs = bias[n];
      int t2 = n >> 4, kg = (n >> 3) & 1, j = n & 7;
#pragma unroll
      for (int r = 0; r < 16; ++r) {
        int row = (r & 3) + 8 * (r >> 2) + 4 * (lane >> 5);
        int m = mt * 32 + row;
        float v = fmaxf(acc[mt][nt][r] + bs, 0.0f);
        _Float16 hi = (_Float16)v;
        _Float16 lo = (_Float16)(v - (float)hi);
        int addr = ((m >> 5) * 16 + t2) * 528 + (m & 31) * 8 + kg * 264 + j;
        oHi[addr] = hi;
        oLo[addr] = lo;
      }
    }
  __syncthreads();
}

#define BUFB 33792  // els; each buffer holds hi+lo planes for K up to 256

__global__ __launch_bounds__(256, 1) void bagnet_mfma(
    const float* __restrict__ gx, const float* __restrict__ gm,
    const float* __restrict__ gu,
    const float* __restrict__ gb1, const float* __restrict__ gb2,
    const float* __restrict__ gb3, const float* __restrict__ gdb1,
    const float* __restrict__ gdb2, const float* __restrict__ gD3,
    const float* __restrict__ gdb3, const float* __restrict__ gE,
    const float* __restrict__ geb, const _Float16* __restrict__ ws,
    float* __restrict__ outw, float* __restrict__ outv)
{
  extern __shared__ _Float16 lds[];
  __shared__ float sZ[64], sEx[64], sW2s[64], sKeep[64], sE2[64], sWf[64], sRed[128];
  const int tid = threadIdx.x, bag = blockIdx.x;
  const int wave = tid >> 6, lane = tid & 63;
  _Float16* bufA = lds;
  _Float16* bufB = lds + BUFB;

  // P1: x @ W1 -> h1 in bufA (hi@0, lo@16896); x staged in bufB
  phase1(gx + (size_t)bag * CROWS * IND, ws + W1HI, ws + W1LO, gb1,
         bufB, bufA, bufA + 16896, tid, wave, lane);
  // P2: h1 @ W2 -> h2 in bufB (hi@0, lo@16896)
  gemm_phase<16, 8, 0>(ws + W2HI, ws + W2LO, gb2, bufA, bufA + 16896,
                       bufB, bufB + 16896, wave, lane);
  // P3: h2 @ W3 -> h in bufA (nkt=8: hi@0, lo@8448)
  gemm_phase<16, 4, 0>(ws + W3HI, ws + W3LO, gb3, bufB, bufB + 16896,
                       bufA, bufA + 8448, wave, lane);
  // P4: h @ D1 -> d1 in bufB (nkt=8)
  gemm_phase<8, 4, 1>(ws + D1HI, ws + D1LO, gdb1, bufA, bufA + 8448,
                      bufB, bufB + 8448, wave, lane);
  // P5: d1 @ D2 -> d2 in bufA+16896 (nkt=4: hi@16896, lo@21120)
  gemm_phase<8, 2, 1>(ws + D2HI, ws + D2LO, gdb2, bufB, bufB + 8448,
                      bufA + 16896, bufA + 16896 + 4224, wave, lane);

  const _Float16* d2H = bufA + 16896;
  const _Float16* d2L = bufA + 21120;
  const _Float16* hH  = bufA;
  const _Float16* hL  = bufA + 8448;

  // ---------------- logits + gumbel softmax (fp32, verified tail) ----------
  if (tid < CROWS) {
    float a = gdb3[0];
    for (int k = 0; k < 64; ++k) {
      int addr = ((tid >> 5) * 4 + (k >> 4)) * 528 + (tid & 31) * 8 + ((k >> 3) & 1) * 264 + (k & 7);
      a = fmaf((float)d2H[addr] + (float)d2L[addr], gD3[k], a);
    }
    float logit = gm[(size_t)bag * CROWS + tid] * a;
    float uu = gu[(size_t)bag * CROWS + tid];
    float g = -logf(-logf(uu));
    sZ[tid] = (logit + g) * (1.0f / TAUV);
  }
  __syncthreads();
  if (tid < CROWS) {
    float mx = -1e30f;
    for (int j = 0; j < CROWS; ++j) mx = fmaxf(mx, sZ[j]);
    sEx[tid] = expf(sZ[tid] - mx);
  }
  __syncthreads();
  float w2 = 0.0f;
  if (tid < CROWS) {
    float s = 0.0f;
    for (int j = 0; j < CROWS; ++j) s += sEx[j];
    w2 = sEx[tid] / s;
    sW2s[tid] = w2;
  }
  __syncthreads();
  // stable top-20 keep (rank >= 44 ascending, stable tie by index)
  int keep = 0;
  if (tid < CROWS) {
    int cnt = 0;
    for (int j = 0; j < CROWS; ++j) {
      float vj = sW2s[j];
      cnt += (vj < w2) || (vj == w2 && j < tid);
    }
    keep = (cnt >= KDROP) ? 1 : 0;
    sKeep[tid] = (float)keep;
  }
  __syncthreads();
  float e2 = 0.0f;
  if (tid < CROWS) {
    float mk = -1e30f;
    for (int j = 0; j < CROWS; ++j)
      if (sKeep[j] > 0.5f) mk = fmaxf(mk, sW2s[j]);
    e2 = keep ? expf(w2 - mk) : 0.0f;
    sE2[tid] = e2;
  }
  __syncthreads();
  if (tid < CROWS) {
    float s2 = 0.0f;
    for (int j = 0; j < CROWS; ++j) s2 += sE2[j];
    float wf = keep ? (e2 / s2) : 0.0f;
    sWf[tid] = wf;
    outw[(size_t)bag * CROWS + tid] = wf;
  }
  __syncthreads();
  // agg = w @ h ; out = agg @ E + eb
  if (tid < 128) {
    float a = 0.0f;
    for (int r = 0; r < CROWS; ++r) {
      int addr = ((r >> 5) * 8 + (tid >> 4)) * 528 + (r & 31) * 8 + ((tid >> 3) & 1) * 264 + (tid & 7);
      a = fmaf(sWf[r], (float)hH[addr] + (float)hL[addr], a);
    }
    sRed[tid] = a * gE[tid];
  }
  __syncthreads();
  if (tid == 0) {
    float s = geb[0];
    for (int j = 0; j < 128; ++j) s += sRed[j];
    outv[bag] = s;
  }
}

extern "C" void kernel_launch(void* const* d_in, const int* in_sizes, int n_in,
                              void* d_out, int out_size, void* d_ws, size_t ws_size,
                              hipStream_t stream) {
  (void)in_sizes; (void)n_in; (void)out_size; (void)ws_size;
  const float* x   = (const float*)d_in[0];
  const float* m   = (const float*)d_in[1];
  const float* u   = (const float*)d_in[2];
  const float* W1  = (const float*)d_in[3];
  const float* b1  = (const float*)d_in[4];
  const float* W2  = (const float*)d_in[5];
  const float* b2  = (const float*)d_in[6];
  const float* W3  = (const float*)d_in[7];
  const float* b3  = (const float*)d_in[8];
  const float* D1  = (const float*)d_in[9];
  const float* db1 = (const float*)d_in[10];
  const float* D2  = (const float*)d_in[11];
  const float* db2 = (const float*)d_in[12];
  const float* D3  = (const float*)d_in[13];
  const float* db3 = (const float*)d_in[14];
  const float* E   = (const float*)d_in[15];
  const float* eb  = (const float*)d_in[16];
  float* outw = (float*)d_out;
  float* outv = outw + (size_t)NBAGS * CROWS;
  _Float16* ws = (_Float16*)d_ws;

  // weights -> hi/lo fp16 fragment planes (every launch; ws is re-poisoned)
  prep_weights<<<992, 256, 0, stream>>>(W1, W2, W3, D1, D2, ws);

  const size_t smem = 2 * (size_t)BUFB * sizeof(_Float16);  // 135168 B
  (void)hipFuncSetAttribute((const void*)bagnet_mfma,
                            hipFuncAttributeMaxDynamicSharedMemorySize, (int)smem);
  bagnet_mfma<<<NBAGS, 256, smem, stream>>>(
      x, m, u, b1, b2, b3, db1, db2, D3, db3, E, eb, ws, outw, outv);
}

// Round 3
// 685.667 us; speedup vs baseline: 2.7743x; 1.1547x over previous
//
#include <hip/hip_runtime.h>
#include <math.h>

#define NBAGS 2048
#define CROWS 64
#define IND   512
#define TAUV  0.95f
#define KDROP 44   // int(64*0.7)

typedef _Float16 h8  __attribute__((ext_vector_type(8)));
typedef _Float16 h4  __attribute__((ext_vector_type(4)));
typedef float    f16v __attribute__((ext_vector_type(16)));

#define MFMA16(a, b, c) __builtin_amdgcn_mfma_f32_32x32x16_f16(a, b, c, 0, 0, 0)

// ---------------------------------------------------------------------------
// Fragment-order layout for an MFMA operand plane (A: [m][k], B: [n][k]).
//   addr = (tile*nkt + (k>>4))*528 + (idx&31)*8 + ((k>>3)&1)*264 + (k&7)
// 528 = 2*264 staggers the kg-halves so epilogue b16 scatters are ≤2-way
// (free per m136); lane reads are 16B-aligned b128, conflict-free.
// ---------------------------------------------------------------------------
__device__ __forceinline__ int frag_roff(int lane, int tile, int t, int nkt) {
  return (tile * nkt + t) * 528 + (lane & 31) * 8 + (lane >> 5) * 264;
}

// ws element offsets (in _Float16 units). plane = (N/32)*nkt*528.
#define W1HI 0
#define W1LO 135168
#define W2HI 270336
#define W2LO 337920
#define W3HI 405504
#define W3LO 439296
#define D1HI 473088
#define D1LO 489984
#define D2HI 506880
#define D2LO 515328
#define WS_ELS 523776  // ~1.05 MB

__global__ __launch_bounds__(256) void prep_weights(
    const float* __restrict__ W1, const float* __restrict__ W2,
    const float* __restrict__ W3, const float* __restrict__ D1,
    const float* __restrict__ D2, _Float16* __restrict__ ws)
{
  int e = blockIdx.x * 256 + threadIdx.x;
  const float* src; int local, nlog, nkt, offH, offL;
  if (e < 131072)      { src = W1; local = e;          nlog = 8; nkt = 32; offH = W1HI; offL = W1LO; }
  else if (e < 196608) { src = W2; local = e - 131072; nlog = 8; nkt = 16; offH = W2HI; offL = W2LO; }
  else if (e < 229376) { src = W3; local = e - 196608; nlog = 7; nkt = 16; offH = W3HI; offL = W3LO; }
  else if (e < 245760) { src = D1; local = e - 229376; nlog = 7; nkt = 8;  offH = D1HI; offL = D1LO; }
  else if (e < 253952) { src = D2; local = e - 245760; nlog = 6; nkt = 8;  offH = D2HI; offL = D2LO; }
  else return;
  int k = local >> nlog;
  int n = local & ((1 << nlog) - 1);
  float w = src[local];
  _Float16 hi = (_Float16)w;
  _Float16 lo = (_Float16)(w - (float)hi);
  int addr = ((n >> 5) * nkt + (k >> 4)) * 528 + (n & 31) * 8 + ((k >> 3) & 1) * 264 + (k & 7);
  ws[offH + addr] = hi;
  ws[offL + addr] = lo;
}

// ---------------------------------------------------------------------------
// Generic phase, 8 waves: wave -> (mt = w&1, nt-group). B register-prefetched
// one k-step ahead (hides L2 latency behind the MFMA block).
// ---------------------------------------------------------------------------
template<int NKT, int NTILES, int ACT>   // NKT=K/16, NTILES=N/32
__device__ __forceinline__ void gemm_phase(
    const _Float16* __restrict__ bHi, const _Float16* __restrict__ bLo,
    const float* __restrict__ bias,
    const _Float16* aHi, const _Float16* aLo,
    _Float16* oHi, _Float16* oLo,
    int wave, int lane)
{
  constexpr int NN   = (NTILES == 8) ? 2 : 1;
  constexpr int ONKT = NTILES * 2;
  const int mt  = wave & 1;
  const int nt0 = (NTILES == 8) ? ((wave >> 1) * 2) : (wave >> 1);
  const bool active = (NTILES == 2) ? (wave < 4) : true;
  f16v acc[NN] = {};
  if (active) {
    h8 bh[NN], bl[NN], bhn[NN], bln[NN];
#pragma unroll
    for (int q = 0; q < NN; ++q) {
      int boff = frag_roff(lane, nt0 + q, 0, NKT);
      bh[q] = *(const h8*)(bHi + boff);
      bl[q] = *(const h8*)(bLo + boff);
    }
#pragma unroll 2
    for (int t = 0; t < NKT; ++t) {
      if (t + 1 < NKT) {
#pragma unroll
        for (int q = 0; q < NN; ++q) {
          int boff = frag_roff(lane, nt0 + q, t + 1, NKT);
          bhn[q] = *(const h8*)(bHi + boff);
          bln[q] = *(const h8*)(bLo + boff);
        }
      }
      int aoff = frag_roff(lane, mt, t, NKT);
      h8 ah = *(const h8*)(aHi + aoff);
      h8 al = *(const h8*)(aLo + aoff);
#pragma unroll
      for (int q = 0; q < NN; ++q) {
        acc[q] = MFMA16(ah, bh[q], acc[q]);
        acc[q] = MFMA16(ah, bl[q], acc[q]);
        acc[q] = MFMA16(al, bh[q], acc[q]);
      }
#pragma unroll
      for (int q = 0; q < NN; ++q) { bh[q] = bhn[q]; bl[q] = bln[q]; }
    }
    // epilogue: C/D layout col=lane&31, row=(r&3)+8*(r>>2)+4*(lane>>5)
#pragma unroll
    for (int q = 0; q < NN; ++q) {
      int n = (nt0 + q) * 32 + (lane & 31);
      float bs = bias[n];
      int t2 = n >> 4, kg = (n >> 3) & 1, j = n & 7;
#pragma unroll
      for (int r = 0; r < 16; ++r) {
        int row = (r & 3) + 8 * (r >> 2) + 4 * (lane >> 5);
        int m = mt * 32 + row;
        float v = acc[q][r] + bs;
        v = (ACT == 0) ? fmaxf(v, 0.0f) : (1.0f / (1.0f + expf(-v)));
        _Float16 hi = (_Float16)v;
        _Float16 lo = (_Float16)(v - (float)hi);
        int addr = ((m >> 5) * ONKT + t2) * 528 + (m & 31) * 8 + kg * 264 + j;
        oHi[addr] = hi;
        oLo[addr] = lo;
      }
    }
  }
  __syncthreads();
}

// ---------------------------------------------------------------------------
// Phase 1: x (fp32 HBM) @ W1 -> h1. 64-k chunks, double-buffered staging with
// explicit register prefetch: load(c+1) -> compute(c) -> cvt/store(c+1).
// ---------------------------------------------------------------------------
__device__ __forceinline__ void phase1(
    const float* __restrict__ xg,
    const _Float16* __restrict__ bHi, const _Float16* __restrict__ bLo,
    const float* __restrict__ bias,
    _Float16* xs,                 // staging: 2 bufs x (hi 4224 + lo 4224) els
    _Float16* oHi, _Float16* oLo, // h1 planes (ONKT=16)
    int tid, int wave, int lane)
{
  const int mt  = wave & 1;
  const int nt0 = (wave >> 1) * 2;
  f16v acc[2] = {};
  float4 xv[2];

  auto loadx = [&](int c) {
#pragma unroll
    for (int it = 0; it < 2; ++it) {
      int flat = it * 512 + tid;
      int row = flat >> 4, c4 = flat & 15;
      xv[it] = *(const float4*)(xg + row * 512 + c * 64 + c4 * 4);
    }
  };
  auto storex = [&](int c) {
    _Float16* sHi = xs + (c & 1) * 8448;
    _Float16* sLo = sHi + 4224;
#pragma unroll
    for (int it = 0; it < 2; ++it) {
      int flat = it * 512 + tid;
      int row = flat >> 4, c4 = flat & 15;
      int t = c4 >> 2, kg = (c4 >> 1) & 1, j0 = (c4 & 1) * 4;
      int addr = ((row >> 5) * 4 + t) * 528 + (row & 31) * 8 + kg * 264 + j0;
      float4 v = xv[it];
      h4 hi, lo;
      hi[0] = (_Float16)v.x; lo[0] = (_Float16)(v.x - (float)hi[0]);
      hi[1] = (_Float16)v.y; lo[1] = (_Float16)(v.y - (float)hi[1]);
      hi[2] = (_Float16)v.z; lo[2] = (_Float16)(v.z - (float)hi[2]);
      hi[3] = (_Float16)v.w; lo[3] = (_Float16)(v.w - (float)hi[3]);
      *(h4*)(sHi + addr) = hi;
      *(h4*)(sLo + addr) = lo;
    }
  };

  h8 bh[2], bl[2], bhn[2], bln[2];
#pragma unroll
  for (int q = 0; q < 2; ++q) {
    int boff = frag_roff(lane, nt0 + q, 0, 32);
    bh[q] = *(const h8*)(bHi + boff);
    bl[q] = *(const h8*)(bLo + boff);
  }

  loadx(0);
  storex(0);
  __syncthreads();
  for (int c = 0; c < 8; ++c) {
    if (c < 7) loadx(c + 1);   // HBM loads in flight across the MFMA block
    const _Float16* sHi = xs + (c & 1) * 8448;
    const _Float16* sLo = sHi + 4224;
#pragma unroll
    for (int t = 0; t < 4; ++t) {
      int tg = c * 4 + t;
      if (tg + 1 < 32) {
#pragma unroll
        for (int q = 0; q < 2; ++q) {
          int boff = frag_roff(lane, nt0 + q, tg + 1, 32);
          bhn[q] = *(const h8*)(bHi + boff);
          bln[q] = *(const h8*)(bLo + boff);
        }
      }
      int aoff = frag_roff(lane, mt, t, 4);
      h8 ah = *(const h8*)(sHi + aoff);
      h8 al = *(const h8*)(sLo + aoff);
#pragma unroll
      for (int q = 0; q < 2; ++q) {
        acc[q] = MFMA16(ah, bh[q], acc[q]);
        acc[q] = MFMA16(ah, bl[q], acc[q]);
        acc[q] = MFMA16(al, bh[q], acc[q]);
      }
#pragma unroll
      for (int q = 0; q < 2; ++q) { bh[q] = bhn[q]; bl[q] = bln[q]; }
    }
    if (c < 7) storex(c + 1);
    __syncthreads();
  }
  // epilogue -> h1 planes (ONKT = 16)
#pragma unroll
  for (int q = 0; q < 2; ++q) {
    int n = (nt0 + q) * 32 + (lane & 31);
    float bs = bias[n];
    int t2 = n >> 4, kg = (n >> 3) & 1, j = n & 7;
#pragma unroll
    for (int r = 0; r < 16; ++r) {
      int row = (r & 3) + 8 * (r >> 2) + 4 * (lane >> 5);
      int m = mt * 32 + row;
      float v = fmaxf(acc[q][r] + bs, 0.0f);
      _Float16 hi = (_Float16)v;
      _Float16 lo = (_Float16)(v - (float)hi);
      int addr = ((m >> 5) * 16 + t2) * 528 + (m & 31) * 8 + kg * 264 + j;
      oHi[addr] = hi;
      oLo[addr] = lo;
    }
  }
  __syncthreads();
}

#define BUFB 33792  // els per buffer (hi+lo planes for K up to 256)

__global__ __launch_bounds__(512, 1) void bagnet_mfma(
    const float* __restrict__ gx, const float* __restrict__ gm,
    const float* __restrict__ gu,
    const float* __restrict__ gb1, const float* __restrict__ gb2,
    const float* __restrict__ gb3, const float* __restrict__ gdb1,
    const float* __restrict__ gdb2, const float* __restrict__ gD3,
    const float* __restrict__ gdb3, const float* __restrict__ gE,
    const float* __restrict__ geb, const _Float16* __restrict__ ws,
    float* __restrict__ outw, float* __restrict__ outv)
{
  extern __shared__ _Float16 lds[];
  __shared__ float sZ[64], sEx[64], sW2s[64], sKeep[64], sE2[64], sWf[64], sRed[128];
  const int tid = threadIdx.x, bag = blockIdx.x;
  const int wave = tid >> 6, lane = tid & 63;
  _Float16* bufA = lds;
  _Float16* bufB = lds + BUFB;

  // P1: x @ W1 -> h1 in bufA (hi@0, lo@16896); x staged in bufB
  phase1(gx + (size_t)bag * CROWS * IND, ws + W1HI, ws + W1LO, gb1,
         bufB, bufA, bufA + 16896, tid, wave, lane);
  // P2: h1 @ W2 -> h2 in bufB (hi@0, lo@16896)
  gemm_phase<16, 8, 0>(ws + W2HI, ws + W2LO, gb2, bufA, bufA + 16896,
                       bufB, bufB + 16896, wave, lane);
  // P3: h2 @ W3 -> h in bufA (hi@0, lo@8448)
  gemm_phase<16, 4, 0>(ws + W3HI, ws + W3LO, gb3, bufB, bufB + 16896,
                       bufA, bufA + 8448, wave, lane);
  // P4: h @ D1 -> d1 in bufB (hi@0, lo@8448)
  gemm_phase<8, 4, 1>(ws + D1HI, ws + D1LO, gdb1, bufA, bufA + 8448,
                      bufB, bufB + 8448, wave, lane);
  // P5: d1 @ D2 -> d2 in bufA+16896 (hi), +21120 (lo); h in bufA@0 intact
  gemm_phase<8, 2, 1>(ws + D2HI, ws + D2LO, gdb2, bufB, bufB + 8448,
                      bufA + 16896, bufA + 16896 + 4224, wave, lane);

  const _Float16* d2H = bufA + 16896;
  const _Float16* d2L = bufA + 21120;
  const _Float16* hH  = bufA;
  const _Float16* hL  = bufA + 8448;

  // ---------------- logits + gumbel softmax (fp32, verified tail) ----------
  if (tid < CROWS) {
    float a = gdb3[0];
    for (int k = 0; k < 64; ++k) {
      int addr = ((tid >> 5) * 4 + (k >> 4)) * 528 + (tid & 31) * 8 + ((k >> 3) & 1) * 264 + (k & 7);
      a = fmaf((float)d2H[addr] + (float)d2L[addr], gD3[k], a);
    }
    float logit = gm[(size_t)bag * CROWS + tid] * a;
    float uu = gu[(size_t)bag * CROWS + tid];
    float g = -logf(-logf(uu));
    sZ[tid] = (logit + g) * (1.0f / TAUV);
  }
  __syncthreads();
  if (tid < CROWS) {
    float mx = -1e30f;
    for (int j = 0; j < CROWS; ++j) mx = fmaxf(mx, sZ[j]);
    sEx[tid] = expf(sZ[tid] - mx);
  }
  __syncthreads();
  float w2 = 0.0f;
  if (tid < CROWS) {
    float s = 0.0f;
    for (int j = 0; j < CROWS; ++j) s += sEx[j];
    w2 = sEx[tid] / s;
    sW2s[tid] = w2;
  }
  __syncthreads();
  // stable top-20 keep (rank >= 44 ascending, stable tie by index)
  int keep = 0;
  if (tid < CROWS) {
    int cnt = 0;
    for (int j = 0; j < CROWS; ++j) {
      float vj = sW2s[j];
      cnt += (vj < w2) || (vj == w2 && j < tid);
    }
    keep = (cnt >= KDROP) ? 1 : 0;
    sKeep[tid] = (float)keep;
  }
  __syncthreads();
  float e2 = 0.0f;
  if (tid < CROWS) {
    float mk = -1e30f;
    for (int j = 0; j < CROWS; ++j)
      if (sKeep[j] > 0.5f) mk = fmaxf(mk, sW2s[j]);
    e2 = keep ? expf(w2 - mk) : 0.0f;
    sE2[tid] = e2;
  }
  __syncthreads();
  if (tid < CROWS) {
    float s2 = 0.0f;
    for (int j = 0; j < CROWS; ++j) s2 += sE2[j];
    float wf = keep ? (e2 / s2) : 0.0f;
    sWf[tid] = wf;
    outw[(size_t)bag * CROWS + tid] = wf;
  }
  __syncthreads();
  // agg = w @ h ; out = agg @ E + eb
  if (tid < 128) {
    float a = 0.0f;
    for (int r = 0; r < CROWS; ++r) {
      int addr = ((r >> 5) * 8 + (tid >> 4)) * 528 + (r & 31) * 8 + ((tid >> 3) & 1) * 264 + (tid & 7);
      a = fmaf(sWf[r], (float)hH[addr] + (float)hL[addr], a);
    }
    sRed[tid] = a * gE[tid];
  }
  __syncthreads();
  if (tid == 0) {
    float s = geb[0];
    for (int j = 0; j < 128; ++j) s += sRed[j];
    outv[bag] = s;
  }
}

extern "C" void kernel_launch(void* const* d_in, const int* in_sizes, int n_in,
                              void* d_out, int out_size, void* d_ws, size_t ws_size,
                              hipStream_t stream) {
  (void)in_sizes; (void)n_in; (void)out_size; (void)ws_size;
  const float* x   = (const float*)d_in[0];
  const float* m   = (const float*)d_in[1];
  const float* u   = (const float*)d_in[2];
  const float* W1  = (const float*)d_in[3];
  const float* b1  = (const float*)d_in[4];
  const float* W2  = (const float*)d_in[5];
  const float* b2  = (const float*)d_in[6];
  const float* W3  = (const float*)d_in[7];
  const float* b3  = (const float*)d_in[8];
  const float* D1  = (const float*)d_in[9];
  const float* db1 = (const float*)d_in[10];
  const float* D2  = (const float*)d_in[11];
  const float* db2 = (const float*)d_in[12];
  const float* D3  = (const float*)d_in[13];
  const float* db3 = (const float*)d_in[14];
  const float* E   = (const float*)d_in[15];
  const float* eb  = (const float*)d_in[16];
  float* outw = (float*)d_out;
  float* outv = outw + (size_t)NBAGS * CROWS;
  _Float16* ws = (_Float16*)d_ws;

  prep_weights<<<992, 256, 0, stream>>>(W1, W2, W3, D1, D2, ws);

  const size_t smem = 2 * (size_t)BUFB * sizeof(_Float16);  // 135168 B
  (void)hipFuncSetAttribute((const void*)bagnet_mfma,
                            hipFuncAttributeMaxDynamicSharedMemorySize, (int)smem);
  bagnet_mfma<<<NBAGS, 512, smem, stream>>>(
      x, m, u, b1, b2, b3, db1, db2, D3, db3, E, eb, ws, outw, outv);
}

// Round 4
// 652.274 us; speedup vs baseline: 2.9163x; 1.0512x over previous
//
#include <hip/hip_runtime.h>
#include <math.h>

#define NBAGS 2048
#define CROWS 64
#define IND   512
#define TAUV  0.95f
#define KDROP 44   // int(64*0.7)

typedef _Float16 h8  __attribute__((ext_vector_type(8)));
typedef _Float16 h4  __attribute__((ext_vector_type(4)));
typedef float    f16v __attribute__((ext_vector_type(16)));

#define MFMA16(a, b, c) __builtin_amdgcn_mfma_f32_32x32x16_f16(a, b, c, 0, 0, 0)

// ---------------------------------------------------------------------------
// Fragment-order layout for an MFMA operand plane (A: [m][k], B: [n][k]).
//   addr = (tile*nkt + (k>>4))*528 + (idx&31)*8 + ((k>>3)&1)*264 + (k&7)
// 528 = 2*264 staggers kg-halves: epilogue b16 scatters ≤2-way (free, m136);
// lane reads are 16B-aligned b128, conflict-free.
// ---------------------------------------------------------------------------
__device__ __forceinline__ int frag_roff(int lane, int tile, int t, int nkt) {
  return (tile * nkt + t) * 528 + (lane & 31) * 8 + (lane >> 5) * 264;
}

// ws element offsets (in _Float16 units). plane = (N/32)*nkt*528.
#define W1HI 0
#define W1LO 135168
#define W2HI 270336
#define W2LO 337920
#define W3HI 405504
#define W3LO 439296
#define D1HI 473088
#define D1LO 489984
#define D2HI 506880
#define D2LO 515328
#define WS_ELS 523776  // ~1.05 MB

__global__ __launch_bounds__(256) void prep_weights(
    const float* __restrict__ W1, const float* __restrict__ W2,
    const float* __restrict__ W3, const float* __restrict__ D1,
    const float* __restrict__ D2, _Float16* __restrict__ ws)
{
  int e = blockIdx.x * 256 + threadIdx.x;
  const float* src; int local, nlog, nkt, offH, offL;
  if (e < 131072)      { src = W1; local = e;          nlog = 8; nkt = 32; offH = W1HI; offL = W1LO; }
  else if (e < 196608) { src = W2; local = e - 131072; nlog = 8; nkt = 16; offH = W2HI; offL = W2LO; }
  else if (e < 229376) { src = W3; local = e - 196608; nlog = 7; nkt = 16; offH = W3HI; offL = W3LO; }
  else if (e < 245760) { src = D1; local = e - 229376; nlog = 7; nkt = 8;  offH = D1HI; offL = D1LO; }
  else if (e < 253952) { src = D2; local = e - 245760; nlog = 6; nkt = 8;  offH = D2HI; offL = D2LO; }
  else return;
  int k = local >> nlog;
  int n = local & ((1 << nlog) - 1);
  float w = src[local];
  _Float16 hi = (_Float16)w;
  _Float16 lo = (_Float16)(w - (float)hi);
  int addr = ((n >> 5) * nkt + (k >> 4)) * 528 + (n & 31) * 8 + ((k >> 3) & 1) * 264 + (k & 7);
  ws[offH + addr] = hi;
  ws[offL + addr] = lo;
}

// ---------------------------------------------------------------------------
// Generic phase, 16 waves: wave -> (kh, tile=(mt,nt)), NN=1. Optional 2-way
// K-split (KS): partial waves reduce through float4 LDS scratch (lane-
// contiguous float4 => conflict-free b128). B prefetch depth-2, A depth-1.
// ---------------------------------------------------------------------------
template<int NKT_TOT, int NTILES, int KS, int ACT>   // NKT_TOT=K/16, NTILES=N/32
__device__ __forceinline__ void gemm_phase(
    const _Float16* __restrict__ bHi, const _Float16* __restrict__ bLo,
    const float* __restrict__ bias,
    const _Float16* aHi, const _Float16* aLo,
    _Float16* oHi, _Float16* oLo, float4* scratch,
    int wave, int lane)
{
  constexpr int TILES = 2 * NTILES;
  constexpr int NKTP  = NKT_TOT / KS;
  constexpr int ONKT  = NTILES * 2;
  const int tile = wave & (TILES - 1);
  const int kh   = wave / TILES;
  const int mt = tile & 1, nt = tile >> 1;
  f16v acc = {};
  if (kh < KS) {
    const int t0 = kh * NKTP;
    h8 bhc, blc, bhn, bln, ahc, alc;
    { int bo = frag_roff(lane, nt, t0, NKT_TOT);
      bhc = *(const h8*)(bHi + bo); blc = *(const h8*)(bLo + bo); }
    if constexpr (NKTP > 1) {
      int bo = frag_roff(lane, nt, t0 + 1, NKT_TOT);
      bhn = *(const h8*)(bHi + bo); bln = *(const h8*)(bLo + bo);
    }
    { int ao = frag_roff(lane, mt, t0, NKT_TOT);
      ahc = *(const h8*)(aHi + ao); alc = *(const h8*)(aLo + ao); }
#pragma unroll
    for (int t = 0; t < NKTP; ++t) {
      h8 bhf, blf, ahn, aln;
      if (t + 2 < NKTP) {
        int bo = frag_roff(lane, nt, t0 + t + 2, NKT_TOT);
        bhf = *(const h8*)(bHi + bo); blf = *(const h8*)(bLo + bo);
      }
      if (t + 1 < NKTP) {
        int ao = frag_roff(lane, mt, t0 + t + 1, NKT_TOT);
        ahn = *(const h8*)(aHi + ao); aln = *(const h8*)(aLo + ao);
      }
      acc = MFMA16(ahc, bhc, acc);
      acc = MFMA16(ahc, blc, acc);
      acc = MFMA16(alc, bhc, acc);
      bhc = bhn; blc = bln; bhn = bhf; bln = blf; ahc = ahn; alc = aln;
    }
  }
  if constexpr (KS > 1) {
    if (kh >= 1 && kh < KS) {
#pragma unroll
      for (int r = 0; r < 4; ++r) {
        float4 v = { acc[4*r], acc[4*r+1], acc[4*r+2], acc[4*r+3] };
        scratch[((tile * (KS - 1) + (kh - 1)) * 4 + r) * 64 + lane] = v;
      }
    }
    __syncthreads();
    if (kh == 0) {
#pragma unroll
      for (int s = 0; s < KS - 1; ++s)
#pragma unroll
        for (int r = 0; r < 4; ++r) {
          float4 v = scratch[((tile * (KS - 1) + s) * 4 + r) * 64 + lane];
          acc[4*r] += v.x; acc[4*r+1] += v.y; acc[4*r+2] += v.z; acc[4*r+3] += v.w;
        }
    }
  }
  if (kh == 0) {
    // epilogue: C/D layout col=lane&31, row=(r&3)+8*(r>>2)+4*(lane>>5)
    int n = nt * 32 + (lane & 31);
    float bs = bias[n];
    int t2 = n >> 4, kg = (n >> 3) & 1, j = n & 7;
#pragma unroll
    for (int r = 0; r < 16; ++r) {
      int row = (r & 3) + 8 * (r >> 2) + 4 * (lane >> 5);
      int m = mt * 32 + row;
      float v = acc[r] + bs;
      v = (ACT == 0) ? fmaxf(v, 0.0f) : (1.0f / (1.0f + expf(-v)));
      _Float16 hi = (_Float16)v;
      _Float16 lo = (_Float16)(v - (float)hi);
      int addr = ((m >> 5) * ONKT + t2) * 528 + (m & 31) * 8 + kg * 264 + j;
      oHi[addr] = hi;
      oLo[addr] = lo;
    }
  }
  __syncthreads();
}

// ---------------------------------------------------------------------------
// Phase 1: x (fp32 HBM) @ W1 -> h1. 128-k chunks (4 chunks), double-buffered
// staging: loadx(c+1) -> compute(c) -> storex(c+1) -> barrier.
// ---------------------------------------------------------------------------
__device__ __forceinline__ void phase1(
    const float* __restrict__ xg,
    const _Float16* __restrict__ bHi, const _Float16* __restrict__ bLo,
    const float* __restrict__ bias,
    _Float16* xs,                 // staging: 2 bufs x 16896 els (hi 8448 + lo 8448)
    _Float16* oHi, _Float16* oLo, // h1 planes (ONKT=16)
    int tid, int wave, int lane)
{
  const int mt = wave & 1, nt = wave >> 1;
  f16v acc = {};
  float4 xv[2];

  auto loadx = [&](int c) {
#pragma unroll
    for (int it = 0; it < 2; ++it) {
      int flat = it * 1024 + tid;
      int row = flat >> 5, c4 = flat & 31;
      xv[it] = *(const float4*)(xg + row * 512 + c * 128 + c4 * 4);
    }
  };
  auto storex = [&](int c) {
    _Float16* sHi = xs + (c & 1) * 16896;
    _Float16* sLo = sHi + 8448;
#pragma unroll
    for (int it = 0; it < 2; ++it) {
      int flat = it * 1024 + tid;
      int row = flat >> 5, c4 = flat & 31;
      int t = c4 >> 2, kg = (c4 >> 1) & 1, j0 = (c4 & 1) * 4;
      int addr = ((row >> 5) * 8 + t) * 528 + (row & 31) * 8 + kg * 264 + j0;
      float4 v = xv[it];
      h4 hi, lo;
      hi[0] = (_Float16)v.x; lo[0] = (_Float16)(v.x - (float)hi[0]);
      hi[1] = (_Float16)v.y; lo[1] = (_Float16)(v.y - (float)hi[1]);
      hi[2] = (_Float16)v.z; lo[2] = (_Float16)(v.z - (float)hi[2]);
      hi[3] = (_Float16)v.w; lo[3] = (_Float16)(v.w - (float)hi[3]);
      *(h4*)(sHi + addr) = hi;
      *(h4*)(sLo + addr) = lo;
    }
  };

  // B prefetch depth-2 over the full 32-t plane (rotation carries across chunks)
  h8 bhc, blc, bhn, bln;
  { int bo = frag_roff(lane, nt, 0, 32);
    bhc = *(const h8*)(bHi + bo); blc = *(const h8*)(bLo + bo); }
  { int bo = frag_roff(lane, nt, 1, 32);
    bhn = *(const h8*)(bHi + bo); bln = *(const h8*)(bLo + bo); }

  loadx(0);
  storex(0);
  __syncthreads();
  for (int c = 0; c < 4; ++c) {
    if (c < 3) loadx(c + 1);   // HBM loads in flight across the chunk's MFMA
    const _Float16* sHi = xs + (c & 1) * 16896;
    const _Float16* sLo = sHi + 8448;
    h8 ahc, alc;
    { int ao = frag_roff(lane, mt, 0, 8);
      ahc = *(const h8*)(sHi + ao); alc = *(const h8*)(sLo + ao); }
#pragma unroll
    for (int t = 0; t < 8; ++t) {
      int tg = c * 8 + t;
      h8 bhf, blf, ahn, aln;
      if (tg + 2 < 32) {
        int bo = frag_roff(lane, nt, tg + 2, 32);
        bhf = *(const h8*)(bHi + bo); blf = *(const h8*)(bLo + bo);
      }
      if (t + 1 < 8) {
        int ao = frag_roff(lane, mt, t + 1, 8);
        ahn = *(const h8*)(sHi + ao); aln = *(const h8*)(sLo + ao);
      }
      acc = MFMA16(ahc, bhc, acc);
      acc = MFMA16(ahc, blc, acc);
      acc = MFMA16(alc, bhc, acc);
      bhc = bhn; blc = bln; bhn = bhf; bln = blf; ahc = ahn; alc = aln;
    }
    if (c < 3) storex(c + 1);
    __syncthreads();
  }
  // epilogue -> h1 planes (ONKT = 16)
  int n = nt * 32 + (lane & 31);
  float bs = bias[n];
  int t2 = n >> 4, kg = (n >> 3) & 1, j = n & 7;
#pragma unroll
  for (int r = 0; r < 16; ++r) {
    int row = (r & 3) + 8 * (r >> 2) + 4 * (lane >> 5);
    int m = mt * 32 + row;
    float v = fmaxf(acc[r] + bs, 0.0f);
    _Float16 hi = (_Float16)v;
    _Float16 lo = (_Float16)(v - (float)hi);
    int addr = ((m >> 5) * 16 + t2) * 528 + (m & 31) * 8 + kg * 264 + j;
    oHi[addr] = hi;
    oLo[addr] = lo;
  }
  __syncthreads();
}

#define BUFB 33792  // els per buffer

__global__ __launch_bounds__(1024, 4) void bagnet_mfma(
    const float* __restrict__ gx, const float* __restrict__ gm,
    const float* __restrict__ gu,
    const float* __restrict__ gb1, const float* __restrict__ gb2,
    const float* __restrict__ gb3, const float* __restrict__ gdb1,
    const float* __restrict__ gdb2, const float* __restrict__ gD3,
    const float* __restrict__ gdb3, const float* __restrict__ gE,
    const float* __restrict__ geb, const _Float16* __restrict__ ws,
    float* __restrict__ outw, float* __restrict__ outv)
{
  extern __shared__ _Float16 lds[];
  __shared__ float sZ[64], sEx[64], sW2s[64], sKeep[64], sE2[64], sWf[64], sRed[128];
  const int tid = threadIdx.x, bag = blockIdx.x;
  const int wave = tid >> 6, lane = tid & 63;
  _Float16* bufA = lds;
  _Float16* bufB = lds + BUFB;

  // P1: x @ W1 -> h1 in bufA (hi@0, lo@16896); x staged in bufB
  phase1(gx + (size_t)bag * CROWS * IND, ws + W1HI, ws + W1LO, gb1,
         bufB, bufA, bufA + 16896, tid, wave, lane);
  // P2: h1 @ W2 -> h2 in bufB (hi@0, lo@16896); 16 tiles, no split
  gemm_phase<16, 8, 1, 0>(ws + W2HI, ws + W2LO, gb2, bufA, bufA + 16896,
                          bufB, bufB + 16896, (float4*)bufA, wave, lane);
  // P3: h2 @ W3 -> h in bufA (hi@0, lo@8448); 8 tiles, 2-way K-split,
  //     scratch in bufA els[16896,33792) (dead h1-lo)
  gemm_phase<16, 4, 2, 0>(ws + W3HI, ws + W3LO, gb3, bufB, bufB + 16896,
                          bufA, bufA + 8448, (float4*)(bufA + 16896), wave, lane);
  // P4: h @ D1 -> d1 in bufB (hi@0, lo@8448); scratch bufB els[16896,33792)
  gemm_phase<8, 4, 2, 1>(ws + D1HI, ws + D1LO, gdb1, bufA, bufA + 8448,
                         bufB, bufB + 8448, (float4*)(bufB + 16896), wave, lane);
  // P5: d1 @ D2 -> d2 at bufA+16896 (hi), +21120 (lo); scratch bufA els[25344,33792)
  gemm_phase<8, 2, 2, 1>(ws + D2HI, ws + D2LO, gdb2, bufB, bufB + 8448,
                         bufA + 16896, bufA + 21120, (float4*)(bufA + 25344), wave, lane);

  const _Float16* d2H = bufA + 16896;
  const _Float16* d2L = bufA + 21120;
  const _Float16* hH  = bufA;
  const _Float16* hL  = bufA + 8448;

  // ---------------- logits + gumbel softmax (fp32, verified tail) ----------
  if (tid < CROWS) {
    float a = gdb3[0];
    for (int k = 0; k < 64; ++k) {
      int addr = ((tid >> 5) * 4 + (k >> 4)) * 528 + (tid & 31) * 8 + ((k >> 3) & 1) * 264 + (k & 7);
      a = fmaf((float)d2H[addr] + (float)d2L[addr], gD3[k], a);
    }
    float logit = gm[(size_t)bag * CROWS + tid] * a;
    float uu = gu[(size_t)bag * CROWS + tid];
    float g = -logf(-logf(uu));
    sZ[tid] = (logit + g) * (1.0f / TAUV);
  }
  __syncthreads();
  if (tid < CROWS) {
    float mx = -1e30f;
    for (int j = 0; j < CROWS; ++j) mx = fmaxf(mx, sZ[j]);
    sEx[tid] = expf(sZ[tid] - mx);
  }
  __syncthreads();
  float w2 = 0.0f;
  if (tid < CROWS) {
    float s = 0.0f;
    for (int j = 0; j < CROWS; ++j) s += sEx[j];
    w2 = sEx[tid] / s;
    sW2s[tid] = w2;
  }
  __syncthreads();
  // stable top-20 keep (rank >= 44 ascending, stable tie by index)
  int keep = 0;
  if (tid < CROWS) {
    int cnt = 0;
    for (int j = 0; j < CROWS; ++j) {
      float vj = sW2s[j];
      cnt += (vj < w2) || (vj == w2 && j < tid);
    }
    keep = (cnt >= KDROP) ? 1 : 0;
    sKeep[tid] = (float)keep;
  }
  __syncthreads();
  float e2 = 0.0f;
  if (tid < CROWS) {
    float mk = -1e30f;
    for (int j = 0; j < CROWS; ++j)
      if (sKeep[j] > 0.5f) mk = fmaxf(mk, sW2s[j]);
    e2 = keep ? expf(w2 - mk) : 0.0f;
    sE2[tid] = e2;
  }
  __syncthreads();
  if (tid < CROWS) {
    float s2 = 0.0f;
    for (int j = 0; j < CROWS; ++j) s2 += sE2[j];
    float wf = keep ? (e2 / s2) : 0.0f;
    sWf[tid] = wf;
    outw[(size_t)bag * CROWS + tid] = wf;
  }
  __syncthreads();
  // agg = w @ h ; out = agg @ E + eb
  if (tid < 128) {
    float a = 0.0f;
    for (int r = 0; r < CROWS; ++r) {
      int addr = ((r >> 5) * 8 + (tid >> 4)) * 528 + (r & 31) * 8 + ((tid >> 3) & 1) * 264 + (tid & 7);
      a = fmaf(sWf[r], (float)hH[addr] + (float)hL[addr], a);
    }
    sRed[tid] = a * gE[tid];
  }
  __syncthreads();
  if (tid == 0) {
    float s = geb[0];
    for (int j = 0; j < 128; ++j) s += sRed[j];
    outv[bag] = s;
  }
}

extern "C" void kernel_launch(void* const* d_in, const int* in_sizes, int n_in,
                              void* d_out, int out_size, void* d_ws, size_t ws_size,
                              hipStream_t stream) {
  (void)in_sizes; (void)n_in; (void)out_size; (void)ws_size;
  const float* x   = (const float*)d_in[0];
  const float* m   = (const float*)d_in[1];
  const float* u   = (const float*)d_in[2];
  const float* W1  = (const float*)d_in[3];
  const float* b1  = (const float*)d_in[4];
  const float* W2  = (const float*)d_in[5];
  const float* b2  = (const float*)d_in[6];
  const float* W3  = (const float*)d_in[7];
  const float* b3  = (const float*)d_in[8];
  const float* D1  = (const float*)d_in[9];
  const float* db1 = (const float*)d_in[10];
  const float* D2  = (const float*)d_in[11];
  const float* db2 = (const float*)d_in[12];
  const float* D3  = (const float*)d_in[13];
  const float* db3 = (const float*)d_in[14];
  const float* E   = (const float*)d_in[15];
  const float* eb  = (const float*)d_in[16];
  float* outw = (float*)d_out;
  float* outv = outw + (size_t)NBAGS * CROWS;
  _Float16* ws = (_Float16*)d_ws;

  prep_weights<<<992, 256, 0, stream>>>(W1, W2, W3, D1, D2, ws);

  const size_t smem = 2 * (size_t)BUFB * sizeof(_Float16);  // 135168 B
  (void)hipFuncSetAttribute((const void*)bagnet_mfma,
                            hipFuncAttributeMaxDynamicSharedMemorySize, (int)smem);
  bagnet_mfma<<<NBAGS, 1024, smem, stream>>>(
      x, m, u, b1, b2, b3, db1, db2, D3, db3, E, eb, ws, outw, outv);
}